// Round 1
// baseline (1073.106 us; speedup 1.0000x reference)
//
#include <hip/hip_runtime.h>
#include <hip/hip_bf16.h>
#include <math.h>

#define BB 16384
#define DD 768
#define NROWS (BB + 84)        // batch rows + 20 mag + 16 scale + 48 ctx
#define MP 16512               // NROWS padded to multiple of 128 (129*128)

// Static device scratch (~300 MB) — avoids relying on ws_size.
__device__ float g_A[(size_t)MP * DD];        // input rows to GEMM1: num_enc + table feat rows
__device__ float g_qkv[(size_t)MP * 2304];    // GEMM1 output (q|k|v per row)
__device__ float g_mixed[(size_t)BB * DD];    // attention-mixed v per element
__device__ float g_pre[(size_t)BB * DD];      // GEMM2 output (pre-normalize)
__device__ unsigned g_maxbits;

__device__ inline float gelu_exact(float x) {
    return 0.5f * x * (1.0f + erff(x * 0.70710678118654752440f));
}

__device__ inline float block_sum256(float v, float* sbuf) {
    #pragma unroll
    for (int o = 32; o; o >>= 1) v += __shfl_xor(v, o);
    __syncthreads();
    if ((threadIdx.x & 63) == 0) sbuf[threadIdx.x >> 6] = v;
    __syncthreads();
    return sbuf[0] + sbuf[1] + sbuf[2] + sbuf[3];
}

__global__ void k_init() { g_maxbits = 0u; }

__global__ void k_absmax(const float* __restrict__ number) {
    float v = 0.f;
    for (int i = blockIdx.x * blockDim.x + threadIdx.x; i < BB; i += gridDim.x * blockDim.x)
        v = fmaxf(v, fabsf(number[i]));
    #pragma unroll
    for (int o = 32; o; o >>= 1) v = fmaxf(v, __shfl_xor(v, o));
    __shared__ float sb[4];
    if ((threadIdx.x & 63) == 0) sb[threadIdx.x >> 6] = v;
    __syncthreads();
    if (threadIdx.x == 0) {
        float m = fmaxf(fmaxf(sb[0], sb[1]), fmaxf(sb[2], sb[3]));
        atomicMax(&g_maxbits, __float_as_uint(m));
    }
}

// 128 blocks: 0-19 mag copy, 20-35 scale_emb rows (per sf), 36-83 ctx rows (per sign,sf), 84-127 zero pad rows
__global__ void k_tables(const float* __restrict__ mag_emb,
                         const float* __restrict__ se_w1, const float* __restrict__ se_b1,
                         const float* __restrict__ se_g1, const float* __restrict__ se_bt1,
                         const float* __restrict__ se_w2, const float* __restrict__ se_b2,
                         const float* __restrict__ ce_w, const float* __restrict__ ce_b,
                         const float* __restrict__ ce_g, const float* __restrict__ ce_bt) {
    __shared__ float sbuf[4];
    __shared__ float sh[192];
    const int t = threadIdx.x;
    const int blk = blockIdx.x;
    if (blk < 20) {
        #pragma unroll
        for (int i = 0; i < 3; ++i) {
            int d = t + 256 * i;
            g_A[(size_t)(BB + blk) * DD + d] = mag_emb[blk * DD + d];
        }
    } else if (blk < 36) {
        int sfi = blk - 20;
        float sf = (float)(sfi - 10);
        float pre = 0.f;
        if (t < 192) pre = sf * se_w1[t] + se_b1[t];
        float s = block_sum256(t < 192 ? pre : 0.f, sbuf);
        float m = s / 192.f;
        float dd = (t < 192) ? (pre - m) : 0.f;
        float vv = block_sum256(dd * dd, sbuf);
        float inv = 1.f / sqrtf(vv / 192.f + 1e-5f);
        if (t < 192) sh[t] = gelu_exact((pre - m) * inv * se_g1[t] + se_bt1[t]);
        __syncthreads();
        #pragma unroll
        for (int i = 0; i < 3; ++i) {
            int d = t + 256 * i;
            float acc = se_b2[d];
            for (int j = 0; j < 192; ++j) acc += se_w2[d * 192 + j] * sh[j];
            g_A[(size_t)(BB + 20 + sfi) * DD + d] = acc;
        }
    } else if (blk < 84) {
        int c = blk - 36;
        int si = c >> 4, sfi = c & 15;
        float f0 = (float)(si - 1);
        float f1 = (float)(sfi - 10) / 16.f;
        float pre[3];
        float ps = 0.f;
        #pragma unroll
        for (int i = 0; i < 3; ++i) {
            int d = t + 256 * i;
            pre[i] = f0 * ce_w[2 * d] + f1 * ce_w[2 * d + 1] + ce_b[d];
            ps += pre[i];
        }
        float s = block_sum256(ps, sbuf);
        float m = s / 768.f;
        float qs = 0.f;
        #pragma unroll
        for (int i = 0; i < 3; ++i) { float dd = pre[i] - m; qs += dd * dd; }
        float vv = block_sum256(qs, sbuf);
        float inv = 1.f / sqrtf(vv / 768.f + 1e-5f);
        #pragma unroll
        for (int i = 0; i < 3; ++i) {
            int d = t + 256 * i;
            g_A[(size_t)(BB + 36 + c) * DD + d] = gelu_exact((pre[i] - m) * inv * ce_g[d] + ce_bt[d]);
        }
    } else {
        int row = BB + 84 + (blk - 84);
        if (row < MP) {
            #pragma unroll
            for (int i = 0; i < 3; ++i) g_A[(size_t)row * DD + t + 256 * i] = 0.f;
        }
    }
}

// one wave per element: num_enc row
__global__ void k_numenc(const float* __restrict__ number,
                         const float* __restrict__ ne_w, const float* __restrict__ ne_b,
                         const float* __restrict__ ne_g, const float* __restrict__ ne_bt) {
    const int wid = threadIdx.x >> 6, lane = threadIdx.x & 63;
    const int e = blockIdx.x * 4 + wid;
    const float ma = __uint_as_float(g_maxbits);
    const float x = number[e];
    const float a = x / (ma + 1e-10f);
    const float b = log1pf(fabsf(x)) / (log1pf(ma) + 1e-10f);
    float pre[12];
    float s = 0.f;
    #pragma unroll
    for (int j = 0; j < 12; ++j) {
        int d = lane + 64 * j;
        float2 w = *reinterpret_cast<const float2*>(&ne_w[2 * d]);
        pre[j] = a * w.x + b * w.y + ne_b[d];
        s += pre[j];
    }
    #pragma unroll
    for (int o = 32; o; o >>= 1) s += __shfl_xor(s, o);
    float m = s / 768.f;
    float q = 0.f;
    #pragma unroll
    for (int j = 0; j < 12; ++j) { float dd = pre[j] - m; q += dd * dd; }
    #pragma unroll
    for (int o = 32; o; o >>= 1) q += __shfl_xor(q, o);
    float inv = 1.f / sqrtf(q / 768.f + 1e-5f);
    #pragma unroll
    for (int j = 0; j < 12; ++j) {
        int d = lane + 64 * j;
        g_A[(size_t)e * DD + d] = gelu_exact((pre[j] - m) * inv * ne_g[d] + ne_bt[d]);
    }
}

// C[m][n] = sum_k A[m][k]*W[n][k] + bias[n].  A: which==0 ? g_A : g_mixed ; C: g_qkv : g_pre
template <int BM, int BN, int BK>
__global__ __launch_bounds__(256) void gemm_nt(int which, const float* __restrict__ W,
                                               const float* __restrict__ bias, int N, int K) {
    const float* A = (which == 0) ? g_A : g_mixed;
    float* C = (which == 0) ? g_qkv : g_pre;
    __shared__ float As[BK][BM + 4];
    __shared__ float Ws[BK][BN + 4];
    const int t = threadIdx.x;
    const int m0 = blockIdx.y * BM, n0 = blockIdx.x * BN;
    const int rg = t >> 4, cg = t & 15;
    float acc[8][8];
    #pragma unroll
    for (int r = 0; r < 8; ++r)
        #pragma unroll
        for (int c = 0; c < 8; ++c) acc[r][c] = 0.f;

    for (int k0 = 0; k0 < K; k0 += BK) {
        #pragma unroll
        for (int i = 0; i < (BM * BK) / (256 * 4); ++i) {
            int fid = t + 256 * i;
            int row = fid >> 2;            // BK/4 = 4 float4 per row
            int kq = (fid & 3) * 4;
            const float4 v = *reinterpret_cast<const float4*>(&A[(size_t)(m0 + row) * K + k0 + kq]);
            As[kq + 0][row] = v.x; As[kq + 1][row] = v.y; As[kq + 2][row] = v.z; As[kq + 3][row] = v.w;
        }
        #pragma unroll
        for (int i = 0; i < (BN * BK) / (256 * 4); ++i) {
            int fid = t + 256 * i;
            int row = fid >> 2;
            int kq = (fid & 3) * 4;
            const float4 v = *reinterpret_cast<const float4*>(&W[(size_t)(n0 + row) * K + k0 + kq]);
            Ws[kq + 0][row] = v.x; Ws[kq + 1][row] = v.y; Ws[kq + 2][row] = v.z; Ws[kq + 3][row] = v.w;
        }
        __syncthreads();
        #pragma unroll
        for (int kk = 0; kk < BK; ++kk) {
            float4 a0 = *reinterpret_cast<const float4*>(&As[kk][rg * 8]);
            float4 a1 = *reinterpret_cast<const float4*>(&As[kk][rg * 8 + 4]);
            float4 b0 = *reinterpret_cast<const float4*>(&Ws[kk][cg * 8]);
            float4 b1 = *reinterpret_cast<const float4*>(&Ws[kk][cg * 8 + 4]);
            float av[8] = {a0.x, a0.y, a0.z, a0.w, a1.x, a1.y, a1.z, a1.w};
            float bv[8] = {b0.x, b0.y, b0.z, b0.w, b1.x, b1.y, b1.z, b1.w};
            #pragma unroll
            for (int r = 0; r < 8; ++r)
                #pragma unroll
                for (int c = 0; c < 8; ++c) acc[r][c] += av[r] * bv[c];
        }
        __syncthreads();
    }
    float bv[8];
    #pragma unroll
    for (int c = 0; c < 8; ++c) bv[c] = bias[n0 + cg * 8 + c];
    #pragma unroll
    for (int r = 0; r < 8; ++r) {
        size_t base = (size_t)(m0 + rg * 8 + r) * N + n0 + cg * 8;
        float4 o0 = make_float4(acc[r][0] + bv[0], acc[r][1] + bv[1], acc[r][2] + bv[2], acc[r][3] + bv[3]);
        float4 o1 = make_float4(acc[r][4] + bv[4], acc[r][5] + bv[5], acc[r][6] + bv[6], acc[r][7] + bv[7]);
        *reinterpret_cast<float4*>(&C[base]) = o0;
        *reinterpret_cast<float4*>(&C[base + 4]) = o1;
    }
}

// one block per element: scores over 4x4 tokens per head, softmax, fold wts, mix v
__global__ __launch_bounds__(256) void k_attn(const float* __restrict__ number,
                                              const float* __restrict__ boundaries) {
    const int e = blockIdx.x;
    const int t = threadIdx.x;
    const float x = number[e];
    int bin = 0;
    #pragma unroll
    for (int j = 0; j < 20; ++j) bin += (boundaries[j] < x) ? 1 : 0;
    bin = min(bin, 19);
    float sf = floorf(log10f(fabsf(x) + 1e-10f));
    int sfi = min(max((int)sf + 10, 0), 15);
    int si = (x > 0.f) ? 2 : ((x < 0.f) ? 0 : 1);
    int rows[4] = {e, BB + bin, BB + 20 + sfi, BB + 36 + si * 16 + sfi};

    const int d0 = t * 3;
    float q[4][3], k[4][3], v[4][3];
    #pragma unroll
    for (int i = 0; i < 4; ++i) {
        size_t base = (size_t)rows[i] * 2304 + d0;
        #pragma unroll
        for (int c = 0; c < 3; ++c) {
            q[i][c] = g_qkv[base + c];
            k[i][c] = g_qkv[base + 768 + c];
            v[i][c] = g_qkv[base + 1536 + c];
        }
    }
    const float isq = 1.0f / sqrtf(96.0f);
    float p[4][4];
    #pragma unroll
    for (int i = 0; i < 4; ++i)
        #pragma unroll
        for (int j = 0; j < 4; ++j) {
            float s = q[i][0] * k[j][0] + q[i][1] * k[j][1] + q[i][2] * k[j][2];
            #pragma unroll
            for (int o = 16; o; o >>= 1) s += __shfl_xor(s, o);
            p[i][j] = s * isq;
        }
    const float wt[4] = {0.4f, 0.3f, 0.2f, 0.1f};
    float wtil[4] = {0.f, 0.f, 0.f, 0.f};
    #pragma unroll
    for (int i = 0; i < 4; ++i) {
        float mx = fmaxf(fmaxf(p[i][0], p[i][1]), fmaxf(p[i][2], p[i][3]));
        float ex[4];
        float den = 0.f;
        #pragma unroll
        for (int j = 0; j < 4; ++j) { ex[j] = expf(p[i][j] - mx); den += ex[j]; }
        float idn = 1.f / den;
        #pragma unroll
        for (int j = 0; j < 4; ++j) wtil[j] += wt[i] * ex[j] * idn;
    }
    #pragma unroll
    for (int c = 0; c < 3; ++c) {
        float o = wtil[0] * v[0][c] + wtil[1] * v[1][c] + wtil[2] * v[2][c] + wtil[3] * v[3][c];
        g_mixed[(size_t)e * DD + d0 + c] = o;
    }
}

// one wave per row: scale by softplus, nan guard, L2-normalize
__global__ void k_norm(const float* __restrict__ number, const float* __restrict__ boundaries,
                       const float* __restrict__ ms, const float* __restrict__ temp,
                       float* __restrict__ out) {
    const int wid = threadIdx.x >> 6, lane = threadIdx.x & 63;
    const int e = blockIdx.x * 4 + wid;
    const float x = number[e];
    int bin = 0;
    #pragma unroll
    for (int j = 0; j < 20; ++j) bin += (boundaries[j] < x) ? 1 : 0;
    bin = min(bin, 19);
    float z = ms[bin] / temp[0];
    float sc = (z > 20.f) ? z : log1pf(expf(z));
    float o[12];
    float ss = 0.f;
    #pragma unroll
    for (int j = 0; j < 12; ++j) {
        int d = lane + 64 * j;
        float p = g_pre[(size_t)e * DD + d] * sc;
        if (p != p) p = 0.f;
        o[j] = p;
        ss += p * p;
    }
    #pragma unroll
    for (int ofs = 32; ofs; ofs >>= 1) ss += __shfl_xor(ss, ofs);
    float inv = 1.f / fmaxf(sqrtf(ss), 1e-12f);
    #pragma unroll
    for (int j = 0; j < 12; ++j) {
        int d = lane + 64 * j;
        out[(size_t)e * DD + d] = o[j] * inv;
    }
}

extern "C" void kernel_launch(void* const* d_in, const int* in_sizes, int n_in,
                              void* d_out, int out_size, void* d_ws, size_t ws_size,
                              hipStream_t stream) {
    const float* number      = (const float*)d_in[0];
    const float* boundaries  = (const float*)d_in[1];
    const float* mag_emb     = (const float*)d_in[2];
    const float* se_w1       = (const float*)d_in[3];
    const float* se_b1       = (const float*)d_in[4];
    const float* se_g1       = (const float*)d_in[5];
    const float* se_bt1      = (const float*)d_in[6];
    const float* se_w2       = (const float*)d_in[7];
    const float* se_b2       = (const float*)d_in[8];
    const float* ne_w        = (const float*)d_in[9];
    const float* ne_b        = (const float*)d_in[10];
    const float* ne_g        = (const float*)d_in[11];
    const float* ne_bt       = (const float*)d_in[12];
    const float* ce_w        = (const float*)d_in[13];
    const float* ce_b        = (const float*)d_in[14];
    const float* ce_g        = (const float*)d_in[15];
    const float* ce_bt       = (const float*)d_in[16];
    const float* in_proj_w   = (const float*)d_in[17];
    const float* in_proj_b   = (const float*)d_in[18];
    const float* out_proj_w  = (const float*)d_in[19];
    const float* out_proj_b  = (const float*)d_in[20];
    const float* mag_scale   = (const float*)d_in[21];
    const float* temperature = (const float*)d_in[22];
    float* out = (float*)d_out;

    k_init<<<1, 64, 0, stream>>>();
    k_absmax<<<64, 256, 0, stream>>>(number);
    k_tables<<<128, 256, 0, stream>>>(mag_emb, se_w1, se_b1, se_g1, se_bt1, se_w2, se_b2,
                                      ce_w, ce_b, ce_g, ce_bt);
    k_numenc<<<BB / 4, 256, 0, stream>>>(number, ne_w, ne_b, ne_g, ne_bt);
    gemm_nt<128, 128, 16><<<dim3(2304 / 128, MP / 128), 256, 0, stream>>>(0, in_proj_w, in_proj_b, 2304, 768);
    k_attn<<<BB, 256, 0, stream>>>(number, boundaries);
    gemm_nt<128, 128, 16><<<dim3(768 / 128, BB / 128), 256, 0, stream>>>(1, out_proj_w, out_proj_b, 768, 768);
    k_norm<<<BB / 4, 256, 0, stream>>>(number, boundaries, mag_scale, temperature, out);
}

// Round 4
// 277.850 us; speedup vs baseline: 3.8622x; 3.8622x over previous
//
#include <hip/hip_runtime.h>
#include <hip/hip_bf16.h>
#include <math.h>

#define BB 16384
#define DD 768
#define MP 16512               // 16384 + 84 table rows, padded to 129*128

typedef __attribute__((ext_vector_type(8))) short bf16x8;
typedef __attribute__((ext_vector_type(4))) float f32x4;

// Static device scratch — referenced ONLY from device code (host cannot take
// the address of __device__ globals; that was the round-2/3 crash).
__device__ short g_Abf[(size_t)MP * DD];            // bf16 feats (rows 0..16383 num_enc, 16384..16467 tables, pad 0)
__device__ short g_W[(size_t)2304 * DD];            // bf16 in_proj_w (Wq|Wk|Wv rows)
__device__ short g_WoutBf[(size_t)DD * DD];         // bf16 out_proj_w
__device__ short g_qkv[(size_t)MP * 2304];          // bf16 GEMM1 out: q|k|v per row (no bias)
__device__ short g_mixed[(size_t)BB * DD];          // bf16 attention-mixed v (+bias) per element
__device__ short g_pre[(size_t)BB * DD];            // bf16 GEMM2 out (no bias)
__device__ unsigned g_maxbits;

__device__ inline unsigned short f2bf(float x) {
    union { float f; unsigned u; } v; v.f = x;
    unsigned r = v.u + 0x7fffu + ((v.u >> 16) & 1u);
    return (unsigned short)(r >> 16);
}
__device__ inline float bf2f(unsigned short h) {
    union { unsigned u; float f; } v; v.u = ((unsigned)h) << 16;
    return v.f;
}

__device__ inline float gelu_exact(float x) {
    return 0.5f * x * (1.0f + erff(x * 0.70710678118654752440f));
}

__device__ inline float block_sum256(float v, float* sbuf) {
    #pragma unroll
    for (int o = 32; o; o >>= 1) v += __shfl_xor(v, o);
    __syncthreads();
    if ((threadIdx.x & 63) == 0) sbuf[threadIdx.x >> 6] = v;
    __syncthreads();
    return sbuf[0] + sbuf[1] + sbuf[2] + sbuf[3];
}

__global__ void k_init() { g_maxbits = 0u; }

__global__ void k_absmax(const float* __restrict__ number) {
    float v = 0.f;
    for (int i = blockIdx.x * blockDim.x + threadIdx.x; i < BB; i += gridDim.x * blockDim.x)
        v = fmaxf(v, fabsf(number[i]));
    #pragma unroll
    for (int o = 32; o; o >>= 1) v = fmaxf(v, __shfl_xor(v, o));
    __shared__ float sb[4];
    if ((threadIdx.x & 63) == 0) sb[threadIdx.x >> 6] = v;
    __syncthreads();
    if (threadIdx.x == 0) {
        float m = fmaxf(fmaxf(sb[0], sb[1]), fmaxf(sb[2], sb[3]));
        atomicMax(&g_maxbits, __float_as_uint(m));
    }
}

// blocks: 0-19 mag rows, 20-35 scale rows, 36-83 ctx rows, 84-127 zero pad rows
__global__ void k_tables(const float* __restrict__ mag_emb,
                         const float* __restrict__ se_w1, const float* __restrict__ se_b1,
                         const float* __restrict__ se_g1, const float* __restrict__ se_bt1,
                         const float* __restrict__ se_w2, const float* __restrict__ se_b2,
                         const float* __restrict__ ce_w, const float* __restrict__ ce_b,
                         const float* __restrict__ ce_g, const float* __restrict__ ce_bt) {
    __shared__ float sbuf[4];
    __shared__ float sh[192];
    const int t = threadIdx.x;
    const int blk = blockIdx.x;
    if (blk < 20) {
        #pragma unroll
        for (int i = 0; i < 3; ++i) {
            int d = t + 256 * i;
            g_Abf[(size_t)(BB + blk) * DD + d] = (short)f2bf(mag_emb[blk * DD + d]);
        }
    } else if (blk < 36) {
        int sfi = blk - 20;
        float sf = (float)(sfi - 10);
        float pre = 0.f;
        if (t < 192) pre = sf * se_w1[t] + se_b1[t];
        float s = block_sum256(t < 192 ? pre : 0.f, sbuf);
        float m = s / 192.f;
        float dd = (t < 192) ? (pre - m) : 0.f;
        float vv = block_sum256(dd * dd, sbuf);
        float inv = 1.f / sqrtf(vv / 192.f + 1e-5f);
        if (t < 192) sh[t] = gelu_exact((pre - m) * inv * se_g1[t] + se_bt1[t]);
        __syncthreads();
        #pragma unroll
        for (int i = 0; i < 3; ++i) {
            int d = t + 256 * i;
            float acc = se_b2[d];
            for (int j = 0; j < 192; ++j) acc += se_w2[d * 192 + j] * sh[j];
            g_Abf[(size_t)(BB + 20 + sfi) * DD + d] = (short)f2bf(acc);
        }
    } else if (blk < 84) {
        int c = blk - 36;
        int si = c >> 4, sfi = c & 15;
        float f0 = (float)(si - 1);
        float f1 = (float)(sfi - 10) / 16.f;
        float pre[3];
        float ps = 0.f;
        #pragma unroll
        for (int i = 0; i < 3; ++i) {
            int d = t + 256 * i;
            pre[i] = f0 * ce_w[2 * d] + f1 * ce_w[2 * d + 1] + ce_b[d];
            ps += pre[i];
        }
        float s = block_sum256(ps, sbuf);
        float m = s / 768.f;
        float qs = 0.f;
        #pragma unroll
        for (int i = 0; i < 3; ++i) { float dd = pre[i] - m; qs += dd * dd; }
        float vv = block_sum256(qs, sbuf);
        float inv = 1.f / sqrtf(vv / 768.f + 1e-5f);
        #pragma unroll
        for (int i = 0; i < 3; ++i) {
            int d = t + 256 * i;
            g_Abf[(size_t)(BB + 36 + c) * DD + d] =
                (short)f2bf(gelu_exact((pre[i] - m) * inv * ce_g[d] + ce_bt[d]));
        }
    } else {
        int row = BB + 84 + (blk - 84);
        if (row < MP) {
            #pragma unroll
            for (int i = 0; i < 3; ++i) g_Abf[(size_t)row * DD + t + 256 * i] = 0;
        }
    }
}

// one wave per element: num_enc row (fp32 math, bf16 store)
__global__ void k_numenc(const float* __restrict__ number,
                         const float* __restrict__ ne_w, const float* __restrict__ ne_b,
                         const float* __restrict__ ne_g, const float* __restrict__ ne_bt) {
    const int wid = threadIdx.x >> 6, lane = threadIdx.x & 63;
    const int e = blockIdx.x * 4 + wid;
    const float ma = __uint_as_float(g_maxbits);
    const float x = number[e];
    const float a = x / (ma + 1e-10f);
    const float b = log1pf(fabsf(x)) / (log1pf(ma) + 1e-10f);
    float pre[12];
    float s = 0.f;
    #pragma unroll
    for (int j = 0; j < 12; ++j) {
        int d = lane + 64 * j;
        float2 w = *reinterpret_cast<const float2*>(&ne_w[2 * d]);
        pre[j] = a * w.x + b * w.y + ne_b[d];
        s += pre[j];
    }
    #pragma unroll
    for (int o = 32; o; o >>= 1) s += __shfl_xor(s, o);
    float m = s / 768.f;
    float q = 0.f;
    #pragma unroll
    for (int j = 0; j < 12; ++j) { float dd = pre[j] - m; q += dd * dd; }
    #pragma unroll
    for (int o = 32; o; o >>= 1) q += __shfl_xor(q, o);
    float inv = 1.f / sqrtf(q / 768.f + 1e-5f);
    #pragma unroll
    for (int j = 0; j < 12; ++j) {
        int d = lane + 64 * j;
        g_Abf[(size_t)e * DD + d] = (short)f2bf(gelu_exact((pre[j] - m) * inv * ne_g[d] + ne_bt[d]));
    }
}

// cast full in_proj_w (2304x768) -> g_W bf16
__global__ void k_cast_qkv(const float* __restrict__ in_proj_w) {
    int i = blockIdx.x * blockDim.x + threadIdx.x;   // float4 index
    const float4 v = *reinterpret_cast<const float4*>(&in_proj_w[(size_t)i * 4]);
    ushort4 o;
    o.x = f2bf(v.x); o.y = f2bf(v.y); o.z = f2bf(v.z); o.w = f2bf(v.w);
    *reinterpret_cast<ushort4*>(&g_W[(size_t)i * 4]) = o;
}

__global__ void k_cast_wout(const float* __restrict__ out_proj_w) {
    int i = blockIdx.x * blockDim.x + threadIdx.x;
    const float4 v = *reinterpret_cast<const float4*>(&out_proj_w[(size_t)i * 4]);
    ushort4 o;
    o.x = f2bf(v.x); o.y = f2bf(v.y); o.z = f2bf(v.z); o.w = f2bf(v.w);
    *reinterpret_cast<ushort4*>(&g_WoutBf[(size_t)i * 4]) = o;
}

// C[m][n] = sum_k A[m][k] * B[n][k]  (bf16 in, bf16 out, fp32 MFMA accum)
// which==0: A=g_Abf, B=g_W (2304 rows), C=g_qkv.  which==1: A=g_mixed, B=g_WoutBf, C=g_pre.
// Buffer selection happens IN DEVICE CODE (device globals are not valid host-side args).
// 128x128 tile, BK=32, 4 waves. Register-staged LDS with both-sides XOR swizzle.
__global__ __launch_bounds__(256) void gemm_bt(int which, int N, int K) {
    const short* A = (which == 0) ? g_Abf : g_mixed;
    const short* B = (which == 0) ? g_W : g_WoutBf;
    short* C = (which == 0) ? g_qkv : g_pre;

    __shared__ short As[128 * 32];
    __shared__ short Bs[128 * 32];
    const int t = threadIdx.x;
    const int m0 = blockIdx.y * 128, n0 = blockIdx.x * 128;
    const int wid = t >> 6, lane = t & 63;
    const int wr = (wid >> 1) * 64, wc = (wid & 1) * 64;
    const int fr = lane & 15, ks = lane >> 4;

    f32x4 acc[4][4];
    #pragma unroll
    for (int m = 0; m < 4; ++m)
        #pragma unroll
        for (int n = 0; n < 4; ++n) acc[m][n] = (f32x4){0.f, 0.f, 0.f, 0.f};

    for (int k0 = 0; k0 < K; k0 += 32) {
        #pragma unroll
        for (int i = 0; i < 2; ++i) {
            int L = t + 256 * i;             // logical 16B slot: row = L>>2, slot = L&3
            int row = L >> 2, sl = L & 3;
            int po = row * 64 + ((sl ^ ((row >> 1) & 3)) * 16);   // swizzled phys offset
            bf16x8 va = *(const bf16x8*)(A + (size_t)(m0 + row) * K + k0 + sl * 8);
            bf16x8 vb = *(const bf16x8*)(B + (size_t)(n0 + row) * K + k0 + sl * 8);
            *(bf16x8*)((char*)As + po) = va;
            *(bf16x8*)((char*)Bs + po) = vb;
        }
        __syncthreads();
        bf16x8 af[4], bfr[4];
        #pragma unroll
        for (int m = 0; m < 4; ++m) {
            int row = wr + m * 16 + fr;
            int off = row * 64 + ((ks ^ ((row >> 1) & 3)) * 16);
            af[m] = *(const bf16x8*)((const char*)As + off);
        }
        #pragma unroll
        for (int n = 0; n < 4; ++n) {
            int row = wc + n * 16 + fr;
            int off = row * 64 + ((ks ^ ((row >> 1) & 3)) * 16);
            bfr[n] = *(const bf16x8*)((const char*)Bs + off);
        }
        #pragma unroll
        for (int m = 0; m < 4; ++m)
            #pragma unroll
            for (int n = 0; n < 4; ++n)
                acc[m][n] = __builtin_amdgcn_mfma_f32_16x16x32_bf16(af[m], bfr[n], acc[m][n], 0, 0, 0);
        __syncthreads();
    }

    #pragma unroll
    for (int m = 0; m < 4; ++m)
        #pragma unroll
        for (int n = 0; n < 4; ++n)
            #pragma unroll
            for (int j = 0; j < 4; ++j) {
                int row = m0 + wr + m * 16 + (lane >> 4) * 4 + j;
                int col = n0 + wc + n * 16 + fr;
                C[(size_t)row * N + col] = (short)f2bf(acc[m][n][j]);
            }
}

// fused attention + per-head mix IN V-SPACE. One wave per element; 12 dims/lane;
// head h = lane/8 (96 dims = 8 lanes x 12). Writes mixed_v (incl. v-bias) bf16.
__global__ void k_attn_mix(const float* __restrict__ number, const float* __restrict__ boundaries,
                           const float* __restrict__ in_proj_b) {
    const int wid = threadIdx.x >> 6, lane = threadIdx.x & 63;
    const int e = blockIdx.x * 4 + wid;
    const float x = number[e];
    int bin = 0;
    #pragma unroll
    for (int j = 0; j < 20; ++j) bin += (boundaries[j] < x) ? 1 : 0;
    bin = min(bin, 19);
    float sf = floorf(log10f(fabsf(x) + 1e-10f));
    int sfi = min(max((int)sf + 10, 0), 15);
    int si = (x > 0.f) ? 2 : ((x < 0.f) ? 0 : 1);
    int rows[4] = {e, BB + bin, BB + 20 + sfi, BB + 36 + si * 16 + sfi};

    const int d0 = lane * 12;
    float bq[12], bk[12], bv[12];
    #pragma unroll
    for (int c = 0; c < 12; ++c) {
        bq[c] = in_proj_b[d0 + c];
        bk[c] = in_proj_b[768 + d0 + c];
        bv[c] = in_proj_b[1536 + d0 + c];
    }
    float q[4][12], k[4][12], v[4][12];
    #pragma unroll
    for (int i = 0; i < 4; ++i) {
        const unsigned short* base = (const unsigned short*)&g_qkv[(size_t)rows[i] * 2304 + d0];
        #pragma unroll
        for (int c = 0; c < 12; ++c) {
            q[i][c] = bf2f(base[c]) + bq[c];
            k[i][c] = bf2f(base[768 + c]) + bk[c];
            v[i][c] = bf2f(base[1536 + c]) + bv[c];
        }
    }
    const float isq = 0.1020620726159658f;   // 1/sqrt(96)
    float s[4][4];
    #pragma unroll
    for (int i = 0; i < 4; ++i)
        #pragma unroll
        for (int j = 0; j < 4; ++j) {
            float p = 0.f;
            #pragma unroll
            for (int c = 0; c < 12; ++c) p += q[i][c] * k[j][c];
            p += __shfl_xor(p, 1);
            p += __shfl_xor(p, 2);
            p += __shfl_xor(p, 4);
            s[i][j] = p * isq;
        }
    const float wt[4] = {0.4f, 0.3f, 0.2f, 0.1f};
    float wtil[4] = {0.f, 0.f, 0.f, 0.f};
    #pragma unroll
    for (int i = 0; i < 4; ++i) {
        float mx = fmaxf(fmaxf(s[i][0], s[i][1]), fmaxf(s[i][2], s[i][3]));
        float ex[4], den = 0.f;
        #pragma unroll
        for (int j = 0; j < 4; ++j) { ex[j] = __expf(s[i][j] - mx); den += ex[j]; }
        float idn = wt[i] / den;
        #pragma unroll
        for (int j = 0; j < 4; ++j) wtil[j] += ex[j] * idn;
    }
    #pragma unroll
    for (int c = 0; c < 12; ++c) {
        float o = wtil[0] * v[0][c] + wtil[1] * v[1][c] + wtil[2] * v[2][c] + wtil[3] * v[3][c];
        g_mixed[(size_t)e * DD + d0 + c] = (short)f2bf(o);
    }
}

// one wave per row: add out-proj bias, softplus scale, nan guard, L2-normalize
__global__ void k_norm(const float* __restrict__ number, const float* __restrict__ boundaries,
                       const float* __restrict__ out_proj_b,
                       const float* __restrict__ ms, const float* __restrict__ temp,
                       float* __restrict__ out) {
    const int wid = threadIdx.x >> 6, lane = threadIdx.x & 63;
    const int e = blockIdx.x * 4 + wid;
    const float x = number[e];
    int bin = 0;
    #pragma unroll
    for (int j = 0; j < 20; ++j) bin += (boundaries[j] < x) ? 1 : 0;
    bin = min(bin, 19);
    float z = ms[bin] / temp[0];
    float sc = (z > 20.f) ? z : log1pf(expf(z));
    const int d0 = lane * 12;
    const unsigned short* base = (const unsigned short*)&g_pre[(size_t)e * DD + d0];
    float o[12], ss = 0.f;
    #pragma unroll
    for (int c = 0; c < 12; ++c) {
        float p = (bf2f(base[c]) + out_proj_b[d0 + c]) * sc;
        if (p != p) p = 0.f;
        o[c] = p;
        ss += p * p;
    }
    #pragma unroll
    for (int ofs = 32; ofs; ofs >>= 1) ss += __shfl_xor(ss, ofs);
    float inv = 1.f / fmaxf(sqrtf(ss), 1e-12f);
    #pragma unroll
    for (int c = 0; c < 12; ++c) out[(size_t)e * DD + d0 + c] = o[c] * inv;
}

extern "C" void kernel_launch(void* const* d_in, const int* in_sizes, int n_in,
                              void* d_out, int out_size, void* d_ws, size_t ws_size,
                              hipStream_t stream) {
    const float* number      = (const float*)d_in[0];
    const float* boundaries  = (const float*)d_in[1];
    const float* mag_emb     = (const float*)d_in[2];
    const float* se_w1       = (const float*)d_in[3];
    const float* se_b1       = (const float*)d_in[4];
    const float* se_g1       = (const float*)d_in[5];
    const float* se_bt1      = (const float*)d_in[6];
    const float* se_w2       = (const float*)d_in[7];
    const float* se_b2       = (const float*)d_in[8];
    const float* ne_w        = (const float*)d_in[9];
    const float* ne_b        = (const float*)d_in[10];
    const float* ne_g        = (const float*)d_in[11];
    const float* ne_bt       = (const float*)d_in[12];
    const float* ce_w        = (const float*)d_in[13];
    const float* ce_b        = (const float*)d_in[14];
    const float* ce_g        = (const float*)d_in[15];
    const float* ce_bt       = (const float*)d_in[16];
    const float* in_proj_w   = (const float*)d_in[17];
    const float* in_proj_b   = (const float*)d_in[18];
    const float* out_proj_w  = (const float*)d_in[19];
    const float* out_proj_b  = (const float*)d_in[20];
    const float* mag_scale   = (const float*)d_in[21];
    const float* temperature = (const float*)d_in[22];
    float* out = (float*)d_out;

    k_init<<<1, 64, 0, stream>>>();
    k_absmax<<<64, 256, 0, stream>>>(number);
    k_tables<<<128, 256, 0, stream>>>(mag_emb, se_w1, se_b1, se_g1, se_bt1, se_w2, se_b2,
                                      ce_w, ce_b, ce_g, ce_bt);
    k_numenc<<<BB / 4, 256, 0, stream>>>(number, ne_w, ne_b, ne_g, ne_bt);
    k_cast_qkv<<<1728, 256, 0, stream>>>(in_proj_w);         // 2304*768/4 float4
    k_cast_wout<<<576, 256, 0, stream>>>(out_proj_w);        // 768*768/4 float4
    gemm_bt<<<dim3(2304 / 128, MP / 128), 256, 0, stream>>>(0, 2304, DD);
    k_attn_mix<<<BB / 4, 256, 0, stream>>>(number, boundaries, in_proj_b);
    gemm_bt<<<dim3(DD / 128, BB / 128), 256, 0, stream>>>(1, DD, DD);
    k_norm<<<BB / 4, 256, 0, stream>>>(number, boundaries, out_proj_b, mag_scale, temperature, out);
}

// Round 5
// 274.201 us; speedup vs baseline: 3.9136x; 1.0133x over previous
//
#include <hip/hip_runtime.h>
#include <hip/hip_bf16.h>
#include <math.h>

#define BB 16384
#define DD 768
#define MP 16512               // 16384 + 84 table rows, padded to 129*128

typedef __attribute__((ext_vector_type(8))) short bf16x8;
typedef __attribute__((ext_vector_type(4))) float f32x4;

// Static device scratch — referenced ONLY from device code (host cannot take
// the address of __device__ globals; that was the round-2/3 crash).
__device__ short g_Abf[(size_t)MP * DD];            // bf16 feats (rows 0..16383 num_enc, 16384..16467 tables, pad 0)
__device__ short g_W[(size_t)2304 * DD];            // bf16 in_proj_w (Wq|Wk|Wv rows)
__device__ short g_WoutBf[(size_t)DD * DD];         // bf16 out_proj_w
__device__ short g_qkv[(size_t)MP * 2304];          // bf16 GEMM1 out: q|k|v per row (no bias)
__device__ short g_mixed[(size_t)BB * DD];          // bf16 attention-mixed v (+bias) per element
__device__ short g_pre[(size_t)BB * DD];            // bf16 GEMM2 out (no bias)
__device__ unsigned g_maxbits;

__device__ inline unsigned short f2bf(float x) {
    union { float f; unsigned u; } v; v.f = x;
    unsigned r = v.u + 0x7fffu + ((v.u >> 16) & 1u);
    return (unsigned short)(r >> 16);
}
__device__ inline float bf2f(unsigned short h) {
    union { unsigned u; float f; } v; v.u = ((unsigned)h) << 16;
    return v.f;
}

__device__ inline float gelu_exact(float x) {
    return 0.5f * x * (1.0f + erff(x * 0.70710678118654752440f));
}

__device__ inline float block_sum256(float v, float* sbuf) {
    #pragma unroll
    for (int o = 32; o; o >>= 1) v += __shfl_xor(v, o);
    __syncthreads();
    if ((threadIdx.x & 63) == 0) sbuf[threadIdx.x >> 6] = v;
    __syncthreads();
    return sbuf[0] + sbuf[1] + sbuf[2] + sbuf[3];
}

__global__ void k_init() { g_maxbits = 0u; }

__global__ void k_absmax(const float* __restrict__ number) {
    float v = 0.f;
    for (int i = blockIdx.x * blockDim.x + threadIdx.x; i < BB; i += gridDim.x * blockDim.x)
        v = fmaxf(v, fabsf(number[i]));
    #pragma unroll
    for (int o = 32; o; o >>= 1) v = fmaxf(v, __shfl_xor(v, o));
    __shared__ float sb[4];
    if ((threadIdx.x & 63) == 0) sb[threadIdx.x >> 6] = v;
    __syncthreads();
    if (threadIdx.x == 0) {
        float m = fmaxf(fmaxf(sb[0], sb[1]), fmaxf(sb[2], sb[3]));
        atomicMax(&g_maxbits, __float_as_uint(m));
    }
}

// blocks: 0-19 mag rows, 20-35 scale rows, 36-83 ctx rows, 84-127 zero pad rows
__global__ void k_tables(const float* __restrict__ mag_emb,
                         const float* __restrict__ se_w1, const float* __restrict__ se_b1,
                         const float* __restrict__ se_g1, const float* __restrict__ se_bt1,
                         const float* __restrict__ se_w2, const float* __restrict__ se_b2,
                         const float* __restrict__ ce_w, const float* __restrict__ ce_b,
                         const float* __restrict__ ce_g, const float* __restrict__ ce_bt) {
    __shared__ float sbuf[4];
    __shared__ float sh[192];
    const int t = threadIdx.x;
    const int blk = blockIdx.x;
    if (blk < 20) {
        #pragma unroll
        for (int i = 0; i < 3; ++i) {
            int d = t + 256 * i;
            g_Abf[(size_t)(BB + blk) * DD + d] = (short)f2bf(mag_emb[blk * DD + d]);
        }
    } else if (blk < 36) {
        int sfi = blk - 20;
        float sf = (float)(sfi - 10);
        float pre = 0.f;
        if (t < 192) pre = sf * se_w1[t] + se_b1[t];
        float s = block_sum256(t < 192 ? pre : 0.f, sbuf);
        float m = s / 192.f;
        float dd = (t < 192) ? (pre - m) : 0.f;
        float vv = block_sum256(dd * dd, sbuf);
        float inv = 1.f / sqrtf(vv / 192.f + 1e-5f);
        if (t < 192) sh[t] = gelu_exact((pre - m) * inv * se_g1[t] + se_bt1[t]);
        __syncthreads();
        #pragma unroll
        for (int i = 0; i < 3; ++i) {
            int d = t + 256 * i;
            float acc = se_b2[d];
            for (int j = 0; j < 192; ++j) acc += se_w2[d * 192 + j] * sh[j];
            g_Abf[(size_t)(BB + 20 + sfi) * DD + d] = (short)f2bf(acc);
        }
    } else if (blk < 84) {
        int c = blk - 36;
        int si = c >> 4, sfi = c & 15;
        float f0 = (float)(si - 1);
        float f1 = (float)(sfi - 10) / 16.f;
        float pre[3];
        float ps = 0.f;
        #pragma unroll
        for (int i = 0; i < 3; ++i) {
            int d = t + 256 * i;
            pre[i] = f0 * ce_w[2 * d] + f1 * ce_w[2 * d + 1] + ce_b[d];
            ps += pre[i];
        }
        float s = block_sum256(ps, sbuf);
        float m = s / 768.f;
        float qs = 0.f;
        #pragma unroll
        for (int i = 0; i < 3; ++i) { float dd = pre[i] - m; qs += dd * dd; }
        float vv = block_sum256(qs, sbuf);
        float inv = 1.f / sqrtf(vv / 768.f + 1e-5f);
        #pragma unroll
        for (int i = 0; i < 3; ++i) {
            int d = t + 256 * i;
            g_Abf[(size_t)(BB + 36 + c) * DD + d] =
                (short)f2bf(gelu_exact((pre[i] - m) * inv * ce_g[d] + ce_bt[d]));
        }
    } else {
        int row = BB + 84 + (blk - 84);
        if (row < MP) {
            #pragma unroll
            for (int i = 0; i < 3; ++i) g_Abf[(size_t)row * DD + t + 256 * i] = 0;
        }
    }
}

// one wave per element: num_enc row (fp32 math, bf16 store)
__global__ void k_numenc(const float* __restrict__ number,
                         const float* __restrict__ ne_w, const float* __restrict__ ne_b,
                         const float* __restrict__ ne_g, const float* __restrict__ ne_bt) {
    const int wid = threadIdx.x >> 6, lane = threadIdx.x & 63;
    const int e = blockIdx.x * 4 + wid;
    const float ma = __uint_as_float(g_maxbits);
    const float x = number[e];
    const float a = x / (ma + 1e-10f);
    const float b = log1pf(fabsf(x)) / (log1pf(ma) + 1e-10f);
    float pre[12];
    float s = 0.f;
    #pragma unroll
    for (int j = 0; j < 12; ++j) {
        int d = lane + 64 * j;
        float2 w = *reinterpret_cast<const float2*>(&ne_w[2 * d]);
        pre[j] = a * w.x + b * w.y + ne_b[d];
        s += pre[j];
    }
    #pragma unroll
    for (int o = 32; o; o >>= 1) s += __shfl_xor(s, o);
    float m = s / 768.f;
    float q = 0.f;
    #pragma unroll
    for (int j = 0; j < 12; ++j) { float dd = pre[j] - m; q += dd * dd; }
    #pragma unroll
    for (int o = 32; o; o >>= 1) q += __shfl_xor(q, o);
    float inv = 1.f / sqrtf(q / 768.f + 1e-5f);
    #pragma unroll
    for (int j = 0; j < 12; ++j) {
        int d = lane + 64 * j;
        g_Abf[(size_t)e * DD + d] = (short)f2bf(gelu_exact((pre[j] - m) * inv * ne_g[d] + ne_bt[d]));
    }
}

// cast in_proj_w (2304x768) -> g_W and out_proj_w (768x768) -> g_WoutBf, one kernel.
// grid covers 589824 float4s: first 442368 -> g_W, rest -> g_WoutBf.
__global__ void k_cast_w(const float* __restrict__ in_proj_w, const float* __restrict__ out_proj_w) {
    int i = blockIdx.x * blockDim.x + threadIdx.x;   // float4 index
    const bool second = (i >= 442368);
    const float* src = second ? out_proj_w : in_proj_w;
    short* dst = second ? g_WoutBf : g_W;
    int j = second ? (i - 442368) : i;
    const float4 v = *reinterpret_cast<const float4*>(&src[(size_t)j * 4]);
    ushort4 o;
    o.x = f2bf(v.x); o.y = f2bf(v.y); o.z = f2bf(v.z); o.w = f2bf(v.w);
    *reinterpret_cast<ushort4*>(&dst[(size_t)j * 4]) = o;
}

// C[m][n] = sum_k A[m][k] * B[n][k]  (bf16 in, bf16 out, fp32 MFMA accum)
// which==0: A=g_Abf, B=g_W (2304 rows), C=g_qkv.  which==1: A=g_mixed, B=g_WoutBf, C=g_pre.
// 128x128 tile, BK=32, 4 waves. global_load_lds width=16 staging: LINEAR LDS dest
// (thread t -> byte t*16), INVERSE-swizzled global source, swizzled ds_read
// (both-sides rule #21 / m201 stage_rc pattern). Read side verified 0 conflicts.
__global__ __launch_bounds__(256) void gemm_bt(int which, int N, int K) {
    const short* A = (which == 0) ? g_Abf : g_mixed;
    const short* B = (which == 0) ? g_W : g_WoutBf;
    short* C = (which == 0) ? g_qkv : g_pre;

    __shared__ short As[128 * 32];
    __shared__ short Bs[128 * 32];
    const int t = threadIdx.x;
    const int m0 = blockIdx.y * 128, n0 = blockIdx.x * 128;
    const int wid = t >> 6, lane = t & 63;
    const int wr = (wid >> 1) * 64, wc = (wid & 1) * 64;
    const int fr = lane & 15, ks = lane >> 4;

    f32x4 acc[4][4];
    #pragma unroll
    for (int m = 0; m < 4; ++m)
        #pragma unroll
        for (int n = 0; n < 4; ++n) acc[m][n] = (f32x4){0.f, 0.f, 0.f, 0.f};

    // stage geometry (constant per thread): phys 16B-slot L = t + 256*i at LDS
    // byte L*16; row = L>>2 (64 B rows), phys slot sp = L&3; the logical slot
    // whose data must land there is lsl = sp ^ ((row>>1)&3).
    for (int k0 = 0; k0 < K; k0 += 32) {
        #pragma unroll
        for (int i = 0; i < 2; ++i) {
            int L = t + 256 * i;
            int row = L >> 2, sp = L & 3;
            int lsl = sp ^ ((row >> 1) & 3);
            const short* srcA = A + (size_t)(m0 + row) * K + k0 + lsl * 8;
            const short* srcB = B + (size_t)(n0 + row) * K + k0 + lsl * 8;
            __builtin_amdgcn_global_load_lds(
                (const __attribute__((address_space(1))) unsigned int*)srcA,
                (__attribute__((address_space(3))) unsigned int*)((char*)As + L * 16), 16, 0, 0);
            __builtin_amdgcn_global_load_lds(
                (const __attribute__((address_space(1))) unsigned int*)srcB,
                (__attribute__((address_space(3))) unsigned int*)((char*)Bs + L * 16), 16, 0, 0);
        }
        __syncthreads();
        bf16x8 af[4], bfr[4];
        #pragma unroll
        for (int m = 0; m < 4; ++m) {
            int row = wr + m * 16 + fr;
            int off = row * 64 + ((ks ^ ((row >> 1) & 3)) * 16);
            af[m] = *(const bf16x8*)((const char*)As + off);
        }
        #pragma unroll
        for (int n = 0; n < 4; ++n) {
            int row = wc + n * 16 + fr;
            int off = row * 64 + ((ks ^ ((row >> 1) & 3)) * 16);
            bfr[n] = *(const bf16x8*)((const char*)Bs + off);
        }
        #pragma unroll
        for (int m = 0; m < 4; ++m)
            #pragma unroll
            for (int n = 0; n < 4; ++n)
                acc[m][n] = __builtin_amdgcn_mfma_f32_16x16x32_bf16(af[m], bfr[n], acc[m][n], 0, 0, 0);
        __syncthreads();
    }

    #pragma unroll
    for (int m = 0; m < 4; ++m)
        #pragma unroll
        for (int n = 0; n < 4; ++n)
            #pragma unroll
            for (int j = 0; j < 4; ++j) {
                int row = m0 + wr + m * 16 + (lane >> 4) * 4 + j;
                int col = n0 + wc + n * 16 + fr;
                C[(size_t)row * N + col] = (short)f2bf(acc[m][n][j]);
            }
}

// fused attention + per-head mix IN V-SPACE. One wave per element; 12 dims/lane;
// head h = lane/8 (96 dims = 8 lanes x 12). Writes mixed_v (incl. v-bias) bf16.
__global__ void k_attn_mix(const float* __restrict__ number, const float* __restrict__ boundaries,
                           const float* __restrict__ in_proj_b) {
    const int wid = threadIdx.x >> 6, lane = threadIdx.x & 63;
    const int e = blockIdx.x * 4 + wid;
    const float x = number[e];
    int bin = 0;
    #pragma unroll
    for (int j = 0; j < 20; ++j) bin += (boundaries[j] < x) ? 1 : 0;
    bin = min(bin, 19);
    float sf = floorf(log10f(fabsf(x) + 1e-10f));
    int sfi = min(max((int)sf + 10, 0), 15);
    int si = (x > 0.f) ? 2 : ((x < 0.f) ? 0 : 1);
    int rows[4] = {e, BB + bin, BB + 20 + sfi, BB + 36 + si * 16 + sfi};

    const int d0 = lane * 12;
    float bq[12], bk[12], bv[12];
    #pragma unroll
    for (int c = 0; c < 12; ++c) {
        bq[c] = in_proj_b[d0 + c];
        bk[c] = in_proj_b[768 + d0 + c];
        bv[c] = in_proj_b[1536 + d0 + c];
    }
    float q[4][12], k[4][12], v[4][12];
    #pragma unroll
    for (int i = 0; i < 4; ++i) {
        const unsigned short* base = (const unsigned short*)&g_qkv[(size_t)rows[i] * 2304 + d0];
        #pragma unroll
        for (int c = 0; c < 12; ++c) {
            q[i][c] = bf2f(base[c]) + bq[c];
            k[i][c] = bf2f(base[768 + c]) + bk[c];
            v[i][c] = bf2f(base[1536 + c]) + bv[c];
        }
    }
    const float isq = 0.1020620726159658f;   // 1/sqrt(96)
    float s[4][4];
    #pragma unroll
    for (int i = 0; i < 4; ++i)
        #pragma unroll
        for (int j = 0; j < 4; ++j) {
            float p = 0.f;
            #pragma unroll
            for (int c = 0; c < 12; ++c) p += q[i][c] * k[j][c];
            p += __shfl_xor(p, 1);
            p += __shfl_xor(p, 2);
            p += __shfl_xor(p, 4);
            s[i][j] = p * isq;
        }
    const float wt[4] = {0.4f, 0.3f, 0.2f, 0.1f};
    float wtil[4] = {0.f, 0.f, 0.f, 0.f};
    #pragma unroll
    for (int i = 0; i < 4; ++i) {
        float mx = fmaxf(fmaxf(s[i][0], s[i][1]), fmaxf(s[i][2], s[i][3]));
        float ex[4], den = 0.f;
        #pragma unroll
        for (int j = 0; j < 4; ++j) { ex[j] = __expf(s[i][j] - mx); den += ex[j]; }
        float idn = wt[i] / den;
        #pragma unroll
        for (int j = 0; j < 4; ++j) wtil[j] += ex[j] * idn;
    }
    #pragma unroll
    for (int c = 0; c < 12; ++c) {
        float o = wtil[0] * v[0][c] + wtil[1] * v[1][c] + wtil[2] * v[2][c] + wtil[3] * v[3][c];
        g_mixed[(size_t)e * DD + d0 + c] = (short)f2bf(o);
    }
}

// one wave per row: add out-proj bias, softplus scale, nan guard, L2-normalize
__global__ void k_norm(const float* __restrict__ number, const float* __restrict__ boundaries,
                       const float* __restrict__ out_proj_b,
                       const float* __restrict__ ms, const float* __restrict__ temp,
                       float* __restrict__ out) {
    const int wid = threadIdx.x >> 6, lane = threadIdx.x & 63;
    const int e = blockIdx.x * 4 + wid;
    const float x = number[e];
    int bin = 0;
    #pragma unroll
    for (int j = 0; j < 20; ++j) bin += (boundaries[j] < x) ? 1 : 0;
    bin = min(bin, 19);
    float z = ms[bin] / temp[0];
    float sc = (z > 20.f) ? z : log1pf(expf(z));
    const int d0 = lane * 12;
    const unsigned short* base = (const unsigned short*)&g_pre[(size_t)e * DD + d0];
    float o[12], ss = 0.f;
    #pragma unroll
    for (int c = 0; c < 12; ++c) {
        float p = (bf2f(base[c]) + out_proj_b[d0 + c]) * sc;
        if (p != p) p = 0.f;
        o[c] = p;
        ss += p * p;
    }
    #pragma unroll
    for (int ofs = 32; ofs; ofs >>= 1) ss += __shfl_xor(ss, ofs);
    float inv = 1.f / fmaxf(sqrtf(ss), 1e-12f);
    #pragma unroll
    for (int c = 0; c < 12; ++c) out[(size_t)e * DD + d0 + c] = o[c] * inv;
}

extern "C" void kernel_launch(void* const* d_in, const int* in_sizes, int n_in,
                              void* d_out, int out_size, void* d_ws, size_t ws_size,
                              hipStream_t stream) {
    const float* number      = (const float*)d_in[0];
    const float* boundaries  = (const float*)d_in[1];
    const float* mag_emb     = (const float*)d_in[2];
    const float* se_w1       = (const float*)d_in[3];
    const float* se_b1       = (const float*)d_in[4];
    const float* se_g1       = (const float*)d_in[5];
    const float* se_bt1      = (const float*)d_in[6];
    const float* se_w2       = (const float*)d_in[7];
    const float* se_b2       = (const float*)d_in[8];
    const float* ne_w        = (const float*)d_in[9];
    const float* ne_b        = (const float*)d_in[10];
    const float* ne_g        = (const float*)d_in[11];
    const float* ne_bt       = (const float*)d_in[12];
    const float* ce_w        = (const float*)d_in[13];
    const float* ce_b        = (const float*)d_in[14];
    const float* ce_g        = (const float*)d_in[15];
    const float* ce_bt       = (const float*)d_in[16];
    const float* in_proj_w   = (const float*)d_in[17];
    const float* in_proj_b   = (const float*)d_in[18];
    const float* out_proj_w  = (const float*)d_in[19];
    const float* out_proj_b  = (const float*)d_in[20];
    const float* mag_scale   = (const float*)d_in[21];
    const float* temperature = (const float*)d_in[22];
    float* out = (float*)d_out;

    k_init<<<1, 64, 0, stream>>>();
    k_absmax<<<64, 256, 0, stream>>>(number);
    k_tables<<<128, 256, 0, stream>>>(mag_emb, se_w1, se_b1, se_g1, se_bt1, se_w2, se_b2,
                                      ce_w, ce_b, ce_g, ce_bt);
    k_numenc<<<BB / 4, 256, 0, stream>>>(number, ne_w, ne_b, ne_g, ne_bt);
    k_cast_w<<<2304, 256, 0, stream>>>(in_proj_w, out_proj_w);   // (2304+768)*768/4 float4
    gemm_bt<<<dim3(2304 / 128, MP / 128), 256, 0, stream>>>(0, 2304, DD);
    k_attn_mix<<<BB / 4, 256, 0, stream>>>(number, boundaries, in_proj_b);
    gemm_bt<<<dim3(DD / 128, BB / 128), 256, 0, stream>>>(1, DD, DD);
    k_norm<<<BB / 4, 256, 0, stream>>>(number, boundaries, out_proj_b, mag_scale, temperature, out);
}